// Round 1
// baseline (244.416 us; speedup 1.0000x reference)
//
#include <hip/hip_runtime.h>
#include <math.h>

#define BB 16
#define NN 5000
#define FF 8
#define TT 12
#define EE 160000
#define HH 64
#define FT 96   // F*T
#define EN (EE + NN)

// ---------------- CSR build ----------------

__global__ void k_zero(int* p, int n) {
    int i = blockIdx.x * blockDim.x + threadIdx.x;
    if (i < n) p[i] = 0;
}

__global__ void k_count(const int* __restrict__ dst, int* __restrict__ deg) {
    int i = blockIdx.x * blockDim.x + threadIdx.x;
    if (i < EE) atomicAdd(&deg[dst[i]], 1);
}

__global__ __launch_bounds__(1024) void k_scan(const int* __restrict__ deg,
                                               int* __restrict__ offs,
                                               int* __restrict__ cursor,
                                               float* __restrict__ dinv) {
    __shared__ int s[1024];
    int tid = threadIdx.x;
    int base = tid * 5;
    int cnt[5];
    int part = 0;
#pragma unroll
    for (int j = 0; j < 5; ++j) {
        int n = base + j;
        int c = (n < NN) ? deg[n] + 1 : 0;   // +1 self loop
        cnt[j] = c;
        part += c;
    }
    s[tid] = part;
    __syncthreads();
    for (int d = 1; d < 1024; d <<= 1) {
        int v = (tid >= d) ? s[tid - d] : 0;
        __syncthreads();
        s[tid] += v;
        __syncthreads();
    }
    int run = s[tid] - part;  // exclusive prefix
#pragma unroll
    for (int j = 0; j < 5; ++j) {
        int n = base + j;
        if (n < NN) {
            offs[n] = run;
            cursor[n] = run;
            dinv[n] = rsqrtf((float)cnt[j]);
            run += cnt[j];
        }
    }
    if (tid == 1023) offs[NN] = s[1023];
}

__global__ void k_fill(const int* __restrict__ src, const int* __restrict__ dst,
                       int* cursor, const float* __restrict__ dinv,
                       int* __restrict__ csrc, float* __restrict__ cw) {
    int i = blockIdx.x * blockDim.x + threadIdx.x;
    if (i < EE) {
        int s = src[i], d = dst[i];
        int p = atomicAdd(&cursor[d], 1);
        csrc[p] = s;
        cw[p] = dinv[s] * dinv[d];
    } else if (i < EN) {
        int n = i - EE;
        int p = atomicAdd(&cursor[n], 1);
        csrc[p] = n;
        cw[p] = dinv[n] * dinv[n];
    }
}

// ---------------- fold weights: G = W @ L[:64], C = b @ L[:64] + lb ----------------

__global__ void k_prep(const float* __restrict__ Wz, const float* __restrict__ bz,
                       const float* __restrict__ Lz, const float* __restrict__ lbz,
                       const float* __restrict__ Wh, const float* __restrict__ bh,
                       const float* __restrict__ Lh, const float* __restrict__ lbh,
                       const float* __restrict__ att,
                       float* __restrict__ G, float* __restrict__ C, float* __restrict__ sm) {
    int tid = threadIdx.x;
    for (int idx = tid; idx < 1024; idx += 256) {
        int g = idx >> 9, rem = idx & 511, f = rem >> 6, o = rem & 63;
        const float* W = g ? Wh : Wz;
        const float* L = g ? Lh : Lz;
        float s = 0.f;
        for (int k = 0; k < 64; ++k) s += W[f * 64 + k] * L[k * 64 + o];
        G[idx] = s;
    }
    for (int idx = tid; idx < 128; idx += 256) {
        int g = idx >> 6, o = idx & 63;
        const float* b = g ? bh : bz;
        const float* L = g ? Lh : Lz;
        const float* lb = g ? lbh : lbz;
        float s = lb[o];
        for (int k = 0; k < 64; ++k) s += b[k] * L[k * 64 + o];
        C[idx] = s;
    }
    if (tid == 0) {
        float m = att[0];
        for (int t = 1; t < TT; ++t) m = fmaxf(m, att[t]);
        float e[TT], s = 0.f;
        for (int t = 0; t < TT; ++t) { e[t] = __expf(att[t] - m); s += e[t]; }
        for (int t = 0; t < TT; ++t) sm[t] = e[t] / s;
    }
}

// ---------------- fused gather + gates + attention + fc ----------------
// one 64-lane wave per (b, n); 4 waves per block share the same n

__global__ __launch_bounds__(256) void k_fused(
    const float* __restrict__ x, const int* __restrict__ offs,
    const int* __restrict__ csrc, const float* __restrict__ cw,
    const float* __restrict__ G, const float* __restrict__ C,
    const float* __restrict__ sm, const float* __restrict__ fcW,
    const float* __restrict__ fcb, float* __restrict__ out) {
    __shared__ float xa[4][FT];
    __shared__ float hl[4][HH];
    int wid = threadIdx.x >> 6;
    int lane = threadIdx.x & 63;
    int gw = blockIdx.x * 4 + wid;
    int n = gw >> 4;   // all 4 waves in a block share n
    int b = gw & 15;

    // lane owns elements ft0 = lane and ft1 = 64+lane (lane<32); ft = t*8+f
    int off0 = (lane & 7) * TT + (lane >> 3);
    int off1 = (lane & 7) * TT + 8 + (lane >> 3);
    const float* xb = x + (size_t)b * (NN * FT);

    int r0 = offs[n], r1 = offs[n + 1];
    r0 = __builtin_amdgcn_readfirstlane(r0);
    r1 = __builtin_amdgcn_readfirstlane(r1);

    float acc0 = 0.f, acc1 = 0.f;
    int k = r0;
    for (; k + 1 < r1; k += 2) {
        int s0 = csrc[k], s1 = csrc[k + 1];
        float w0 = cw[k], w1 = cw[k + 1];
        const float* p0 = xb + (size_t)s0 * FT;
        const float* p1 = xb + (size_t)s1 * FT;
        acc0 += w0 * p0[off0] + w1 * p1[off0];
        if (lane < 32) acc1 += w0 * p0[off1] + w1 * p1[off1];
    }
    if (k < r1) {
        int s0 = csrc[k];
        float w0 = cw[k];
        const float* p0 = xb + (size_t)s0 * FT;
        acc0 += w0 * p0[off0];
        if (lane < 32) acc1 += w0 * p0[off1];
    }
    xa[wid][lane] = acc0;
    if (lane < 32) xa[wid][64 + lane] = acc1;
    __syncthreads();

    // dense: lane owns hidden channel o = lane
    float gz[FF], gh[FF];
#pragma unroll
    for (int f = 0; f < FF; ++f) {
        gz[f] = G[f * 64 + lane];
        gh[f] = G[512 + f * 64 + lane];
    }
    float cz = C[lane], ch = C[64 + lane];
    float hacc = 0.f;
#pragma unroll
    for (int t = 0; t < TT; ++t) {
        float az = cz, ah = ch;
#pragma unroll
        for (int f = 0; f < FF; ++f) {
            float v = xa[wid][t * 8 + f];
            az += v * gz[f];
            ah += v * gh[f];
        }
        float z = 1.0f / (1.0f + __expf(-az));
        float th = 1.0f - 2.0f / (__expf(2.0f * ah) + 1.0f);
        hacc += sm[t] * (1.0f - z) * th;
    }
    hl[wid][lane] = hacc;
    __syncthreads();

    if (lane < TT) {
        float s = fcb[lane];
#pragma unroll 8
        for (int o = 0; o < HH; ++o) s += hl[wid][o] * fcW[o * TT + lane];
        out[((size_t)b * NN + n) * TT + lane] = s;
    }
}

extern "C" void kernel_launch(void* const* d_in, const int* in_sizes, int n_in,
                              void* d_out, int out_size, void* d_ws, size_t ws_size,
                              hipStream_t stream) {
    const float* x   = (const float*)d_in[0];
    const int*   ei  = (const int*)d_in[1];
    const float* Wz  = (const float*)d_in[2];
    const float* bz  = (const float*)d_in[3];
    const float* Lz  = (const float*)d_in[4];
    const float* lbz = (const float*)d_in[5];
    // d_in[6..9] = Wr, br, Lr, lbr : dead (H == 0)
    const float* Wh  = (const float*)d_in[10];
    const float* bh  = (const float*)d_in[11];
    const float* Lh  = (const float*)d_in[12];
    const float* lbh = (const float*)d_in[13];
    const float* att = (const float*)d_in[14];
    const float* fcW = (const float*)d_in[15];
    const float* fcb = (const float*)d_in[16];
    float* out = (float*)d_out;

    const int* src = ei;
    const int* dst = ei + EE;

    int*   deg    = (int*)d_ws;            // N
    int*   cursor = deg + NN;              // N
    int*   offs   = cursor + NN;           // N+1
    int*   csrc   = offs + NN + 1;         // E+N
    float* cw     = (float*)(csrc + EN);   // E+N
    float* dinv   = cw + EN;               // N
    float* G      = dinv + NN;             // 2*8*64
    float* C      = G + 1024;              // 2*64
    float* sm     = C + 128;               // T

    hipLaunchKernelGGL(k_zero, dim3((NN + 255) / 256), dim3(256), 0, stream, deg, NN);
    hipLaunchKernelGGL(k_count, dim3((EE + 255) / 256), dim3(256), 0, stream, dst, deg);
    hipLaunchKernelGGL(k_scan, dim3(1), dim3(1024), 0, stream, deg, offs, cursor, dinv);
    hipLaunchKernelGGL(k_fill, dim3((EN + 255) / 256), dim3(256), 0, stream,
                       src, dst, cursor, dinv, csrc, cw);
    hipLaunchKernelGGL(k_prep, dim3(1), dim3(256), 0, stream,
                       Wz, bz, Lz, lbz, Wh, bh, Lh, lbh, att, G, C, sm);
    hipLaunchKernelGGL(k_fused, dim3((BB * NN) / 4), dim3(256), 0, stream,
                       x, offs, csrc, cw, G, C, sm, fcW, fcb, out);
}

// Round 2
// 213.701 us; speedup vs baseline: 1.1437x; 1.1437x over previous
//
#include <hip/hip_runtime.h>
#include <math.h>

#define BB 16
#define NN 5000
#define FF 8
#define TT 12
#define EE 160000
#define HH 64
#define FT 96                    // F*T
#define EN (EE + NN)
#define XBSTRIDE (NN * FT * 4)   // bytes per batch slab of x = 1,920,000

// ---------------- CSR build ----------------

__global__ void k_count(const int* __restrict__ dst, int* __restrict__ deg) {
    int i = blockIdx.x * blockDim.x + threadIdx.x;
    if (i < EE) atomicAdd(&deg[dst[i]], 1);
}

// scan (CSR offsets + dinv) fused with weight folding / softmax prep
__global__ __launch_bounds__(256) void k_scan_prep(
    const int* __restrict__ deg, int* __restrict__ offs, int* __restrict__ cursor,
    float* __restrict__ dinv,
    const float* __restrict__ Wz, const float* __restrict__ bz,
    const float* __restrict__ Lz, const float* __restrict__ lbz,
    const float* __restrict__ Wh, const float* __restrict__ bh,
    const float* __restrict__ Lh, const float* __restrict__ lbh,
    const float* __restrict__ att,
    float* __restrict__ G, float* __restrict__ C, float* __restrict__ sm) {
    __shared__ int s[256];
    int tid = threadIdx.x;
    int base = tid * 20;
    int cnt[20];
    int part = 0;
#pragma unroll
    for (int j = 0; j < 20; ++j) {
        int n = base + j;
        int c = (n < NN) ? deg[n] + 1 : 0;   // +1 self loop
        cnt[j] = c;
        part += c;
    }
    s[tid] = part;
    __syncthreads();
    for (int d = 1; d < 256; d <<= 1) {
        int v = (tid >= d) ? s[tid - d] : 0;
        __syncthreads();
        s[tid] += v;
        __syncthreads();
    }
    int run = s[tid] - part;  // exclusive prefix
#pragma unroll
    for (int j = 0; j < 20; ++j) {
        int n = base + j;
        if (n < NN) {
            offs[n] = run;
            cursor[n] = run;
            dinv[n] = rsqrtf((float)cnt[j]);
            run += cnt[j];
        }
    }
    if (tid == 255) offs[NN] = s[255];

    // ---- weight folding: G = W @ L[:64], C = b @ L[:64] + lb (independent of scan)
    for (int idx = tid; idx < 1024; idx += 256) {
        int g = idx >> 9, rem = idx & 511, f = rem >> 6, o = rem & 63;
        const float* W = g ? Wh : Wz;
        const float* L = g ? Lh : Lz;
        float acc = 0.f;
        for (int k = 0; k < 64; ++k) acc += W[f * 64 + k] * L[k * 64 + o];
        G[idx] = acc;
    }
    for (int idx = tid; idx < 128; idx += 256) {
        int g = idx >> 6, o = idx & 63;
        const float* b = g ? bh : bz;
        const float* L = g ? Lh : Lz;
        const float* lb = g ? lbh : lbz;
        float acc = lb[o];
        for (int k = 0; k < 64; ++k) acc += b[k] * L[k * 64 + o];
        C[idx] = acc;
    }
    if (tid == 0) {
        float m = att[0];
        for (int t = 1; t < TT; ++t) m = fmaxf(m, att[t]);
        float e[TT], ss = 0.f;
        for (int t = 0; t < TT; ++t) { e[t] = __expf(att[t] - m); ss += e[t]; }
        for (int t = 0; t < TT; ++t) sm[t] = e[t] / ss;
    }
}

__global__ void k_fill(const int* __restrict__ src, const int* __restrict__ dst,
                       int* cursor, const float* __restrict__ dinv,
                       int* __restrict__ csrc, float* __restrict__ cw) {
    int i = blockIdx.x * blockDim.x + threadIdx.x;
    if (i < EE) {
        int s = src[i], d = dst[i];
        int p = atomicAdd(&cursor[d], 1);
        csrc[p] = s;
        cw[p] = dinv[s] * dinv[d];
    } else if (i < EN) {
        int n = i - EE;
        int p = atomicAdd(&cursor[n], 1);
        csrc[p] = n;
        cw[p] = dinv[n] * dinv[n];
    }
}

// ---------------- fused gather + gates + attention + fc ----------------
// block (256 thr) = 2 nodes; wave = one node, 8 batches.
// Per edge a wave loads 8 batches x 96 floats = 192 float4 = 3 float4/lane.

__global__ __launch_bounds__(256) void k_fused(
    const float* __restrict__ x, const int* __restrict__ offs,
    const int* __restrict__ csrc, const float* __restrict__ cw,
    const float* __restrict__ G, const float* __restrict__ C,
    const float* __restrict__ sm, const float* __restrict__ fcW,
    const float* __restrict__ fcb, float* __restrict__ out) {
    __shared__ float xals[2][16][96];
    __shared__ float hl[2][16 * 65];   // pad 65 to dodge fc-phase bank conflicts
    const int tid = threadIdx.x;
    const int wid = tid >> 6;
    const int lane = tid & 63;
    const int wn = wid >> 1;           // which node of the block
    const int wp = wid & 1;            // batch half: b in [wp*8, wp*8+8)
    const int n = blockIdx.x * 2 + wn;

    int voff[3], bidx[3], f4idx[3];
#pragma unroll
    for (int j = 0; j < 3; ++j) {
        int item = j * 64 + lane;      // 0..191
        int bs = item / 24;            // 0..7
        int f4 = item - bs * 24;       // 0..23
        bidx[j] = wp * 8 + bs;
        f4idx[j] = f4;
        voff[j] = bidx[j] * XBSTRIDE + f4 * 16;
    }

    int r0 = __builtin_amdgcn_readfirstlane(offs[n]);
    int r1 = __builtin_amdgcn_readfirstlane(offs[n + 1]);

    float4 a0 = {0.f, 0.f, 0.f, 0.f};
    float4 a1 = {0.f, 0.f, 0.f, 0.f};
    float4 a2 = {0.f, 0.f, 0.f, 0.f};
    const char* xc = (const char*)x;

    int k = r0;
    for (; k + 1 < r1; k += 2) {
        int s0 = __builtin_amdgcn_readfirstlane(csrc[k]);
        int s1 = __builtin_amdgcn_readfirstlane(csrc[k + 1]);
        float w0 = cw[k];
        float w1 = cw[k + 1];
        const char* p0 = xc + (size_t)s0 * 384;
        const char* p1 = xc + (size_t)s1 * 384;
        float4 u0 = *(const float4*)(p0 + voff[0]);
        float4 u1 = *(const float4*)(p0 + voff[1]);
        float4 u2 = *(const float4*)(p0 + voff[2]);
        float4 v0 = *(const float4*)(p1 + voff[0]);
        float4 v1 = *(const float4*)(p1 + voff[1]);
        float4 v2 = *(const float4*)(p1 + voff[2]);
        a0.x += w0 * u0.x + w1 * v0.x; a0.y += w0 * u0.y + w1 * v0.y;
        a0.z += w0 * u0.z + w1 * v0.z; a0.w += w0 * u0.w + w1 * v0.w;
        a1.x += w0 * u1.x + w1 * v1.x; a1.y += w0 * u1.y + w1 * v1.y;
        a1.z += w0 * u1.z + w1 * v1.z; a1.w += w0 * u1.w + w1 * v1.w;
        a2.x += w0 * u2.x + w1 * v2.x; a2.y += w0 * u2.y + w1 * v2.y;
        a2.z += w0 * u2.z + w1 * v2.z; a2.w += w0 * u2.w + w1 * v2.w;
    }
    if (k < r1) {
        int s0 = __builtin_amdgcn_readfirstlane(csrc[k]);
        float w0 = cw[k];
        const char* p0 = xc + (size_t)s0 * 384;
        float4 u0 = *(const float4*)(p0 + voff[0]);
        float4 u1 = *(const float4*)(p0 + voff[1]);
        float4 u2 = *(const float4*)(p0 + voff[2]);
        a0.x += w0 * u0.x; a0.y += w0 * u0.y; a0.z += w0 * u0.z; a0.w += w0 * u0.w;
        a1.x += w0 * u1.x; a1.y += w0 * u1.y; a1.z += w0 * u1.z; a1.w += w0 * u1.w;
        a2.x += w0 * u2.x; a2.y += w0 * u2.y; a2.z += w0 * u2.z; a2.w += w0 * u2.w;
    }

    *(float4*)&xals[wn][bidx[0]][f4idx[0] * 4] = a0;
    *(float4*)&xals[wn][bidx[1]][f4idx[1] * 4] = a1;
    *(float4*)&xals[wn][bidx[2]][f4idx[2] * 4] = a2;
    __syncthreads();

    // ---- dense gates: lane owns hidden channel o = lane, loops over its 8 batches
    float gz[FF], gh[FF];
#pragma unroll
    for (int f = 0; f < FF; ++f) {
        gz[f] = G[f * 64 + lane];
        gh[f] = G[512 + f * 64 + lane];
    }
    float cz = C[lane], ch = C[64 + lane];
    float smv[TT];
#pragma unroll
    for (int t = 0; t < TT; ++t) smv[t] = sm[t];

#pragma unroll
    for (int bs = 0; bs < 8; ++bs) {
        int b = wp * 8 + bs;
        float hacc = 0.f;
#pragma unroll
        for (int t = 0; t < TT; ++t) {
            float az = cz, ah = ch;
#pragma unroll
            for (int f = 0; f < FF; ++f) {
                float v = xals[wn][b][f * TT + t];   // broadcast read
                az += v * gz[f];
                ah += v * gh[f];
            }
            float z = 1.0f / (1.0f + __expf(-az));
            float th = 1.0f - 2.0f / (__expf(2.0f * ah) + 1.0f);
            hacc += smv[t] * (1.0f - z) * th;
        }
        hl[wn][b * 65 + lane] = hacc;
    }
    __syncthreads();

    // ---- fc: 2 nodes x 16 b x 12 t = 384 outputs over 256 threads
    for (int u = tid; u < 384; u += 256) {
        int un = u / 192;
        int rem = u - un * 192;
        int b = rem / 12;
        int t = rem - b * 12;
        int nn = blockIdx.x * 2 + un;
        float s = fcb[t];
#pragma unroll 16
        for (int o = 0; o < HH; ++o) s += hl[un][b * 65 + o] * fcW[o * TT + t];
        out[((size_t)b * NN + nn) * TT + t] = s;
    }
}

extern "C" void kernel_launch(void* const* d_in, const int* in_sizes, int n_in,
                              void* d_out, int out_size, void* d_ws, size_t ws_size,
                              hipStream_t stream) {
    const float* x   = (const float*)d_in[0];
    const int*   ei  = (const int*)d_in[1];
    const float* Wz  = (const float*)d_in[2];
    const float* bz  = (const float*)d_in[3];
    const float* Lz  = (const float*)d_in[4];
    const float* lbz = (const float*)d_in[5];
    // d_in[6..9] = Wr, br, Lr, lbr : dead (H == 0)
    const float* Wh  = (const float*)d_in[10];
    const float* bh  = (const float*)d_in[11];
    const float* Lh  = (const float*)d_in[12];
    const float* lbh = (const float*)d_in[13];
    const float* att = (const float*)d_in[14];
    const float* fcW = (const float*)d_in[15];
    const float* fcb = (const float*)d_in[16];
    float* out = (float*)d_out;

    const int* src = ei;
    const int* dst = ei + EE;

    int*   deg    = (int*)d_ws;            // N
    int*   cursor = deg + NN;              // N
    int*   offs   = cursor + NN;           // N+1
    int*   csrc   = offs + NN + 1;         // E+N
    float* cw     = (float*)(csrc + EN);   // E+N
    float* dinv   = cw + EN;               // N
    float* G      = dinv + NN;             // 2*8*64
    float* C      = G + 1024;              // 2*64
    float* sm     = C + 128;               // T

    hipMemsetAsync(deg, 0, NN * sizeof(int), stream);
    hipLaunchKernelGGL(k_count, dim3((EE + 255) / 256), dim3(256), 0, stream, dst, deg);
    hipLaunchKernelGGL(k_scan_prep, dim3(1), dim3(256), 0, stream,
                       deg, offs, cursor, dinv,
                       Wz, bz, Lz, lbz, Wh, bh, Lh, lbh, att, G, C, sm);
    hipLaunchKernelGGL(k_fill, dim3((EN + 255) / 256), dim3(256), 0, stream,
                       src, dst, cursor, dinv, csrc, cw);
    hipLaunchKernelGGL(k_fused, dim3(NN / 2), dim3(256), 0, stream,
                       x, offs, csrc, cw, G, C, sm, fcW, fcb, out);
}

// Round 3
// 190.394 us; speedup vs baseline: 1.2837x; 1.1224x over previous
//
#include <hip/hip_runtime.h>
#include <math.h>

#define BB 16
#define NN 5000
#define FF 8
#define TT 12
#define EE 160000
#define HH 64
#define EN (EE + NN)
#define XBSTRIDE 1920000      // bytes per batch slab of x (N*F*T*4)
#define BSOFF    15360000     // 8 slabs = byte offset from batch b to b+8

// ---------------- CSR build ----------------

__global__ void k_count(const int* __restrict__ dst, int* __restrict__ deg) {
    int i = blockIdx.x * blockDim.x + threadIdx.x;
    if (i < EE) atomicAdd(&deg[dst[i]], 1);
}

// block 0: CSR offsets + dinv scan; block 1: weight folding + softmax
__global__ __launch_bounds__(256) void k_scan_prep(
    const int* __restrict__ deg, int* __restrict__ offs, int* __restrict__ cursor,
    float* __restrict__ dinv,
    const float* __restrict__ Wz, const float* __restrict__ bz,
    const float* __restrict__ Lz, const float* __restrict__ lbz,
    const float* __restrict__ Wh, const float* __restrict__ bh,
    const float* __restrict__ Lh, const float* __restrict__ lbh,
    const float* __restrict__ att,
    float* __restrict__ G, float* __restrict__ C, float* __restrict__ sm) {
    int tid = threadIdx.x;
    if (blockIdx.x == 0) {
        __shared__ int s[256];
        int base = tid * 20;
        int cnt[20];
        int part = 0;
#pragma unroll
        for (int j = 0; j < 20; ++j) {
            int n = base + j;
            int c = (n < NN) ? deg[n] + 1 : 0;   // +1 self loop
            cnt[j] = c;
            part += c;
        }
        s[tid] = part;
        __syncthreads();
        for (int d = 1; d < 256; d <<= 1) {
            int v = (tid >= d) ? s[tid - d] : 0;
            __syncthreads();
            s[tid] += v;
            __syncthreads();
        }
        int run = s[tid] - part;  // exclusive prefix
#pragma unroll
        for (int j = 0; j < 20; ++j) {
            int n = base + j;
            if (n < NN) {
                offs[n] = run;
                cursor[n] = run;
                dinv[n] = rsqrtf((float)cnt[j]);
                run += cnt[j];
            }
        }
        if (tid == 255) offs[NN] = s[255];
    } else {
        // G = W @ L[:64]  (two gates), C = b @ L[:64] + lb
        for (int idx = tid; idx < 1024; idx += 256) {
            int g = idx >> 9, rem = idx & 511, f = rem >> 6, o = rem & 63;
            const float* W = g ? Wh : Wz;
            const float* L = g ? Lh : Lz;
            float acc = 0.f;
            for (int k = 0; k < 64; ++k) acc += W[f * 64 + k] * L[k * 64 + o];
            G[idx] = acc;
        }
        for (int idx = tid; idx < 128; idx += 256) {
            int g = idx >> 6, o = idx & 63;
            const float* b = g ? bh : bz;
            const float* L = g ? Lh : Lz;
            const float* lb = g ? lbh : lbz;
            float acc = lb[o];
            for (int k = 0; k < 64; ++k) acc += b[k] * L[k * 64 + o];
            C[idx] = acc;
        }
        if (tid == 0) {
            float m = att[0];
            for (int t = 1; t < TT; ++t) m = fmaxf(m, att[t]);
            float e[TT], ss = 0.f;
            for (int t = 0; t < TT; ++t) { e[t] = __expf(att[t] - m); ss += e[t]; }
            for (int t = 0; t < TT; ++t) sm[t] = e[t] / ss;
        }
    }
}

__global__ void k_fill(const int* __restrict__ src, const int* __restrict__ dst,
                       int* cursor, const float* __restrict__ dinv,
                       int2* __restrict__ cedge) {
    int i = blockIdx.x * blockDim.x + threadIdx.x;
    if (i < EE) {
        int s = src[i], d = dst[i];
        int p = atomicAdd(&cursor[d], 1);
        cedge[p] = make_int2(s, __float_as_int(dinv[s] * dinv[d]));
    } else if (i < EN) {
        int n = i - EE;
        int p = atomicAdd(&cursor[n], 1);
        cedge[p] = make_int2(n, __float_as_int(dinv[n] * dinv[n]));
    }
}

// ---------------- fused gather + gates + attention + fc ----------------
// blockIdx % 8 = bp  -> XCD bp only touches batches {bp, bp+8}: 3.84 MB, L2-resident.
// block = 4 waves; wave = one node, 2 batches.
// Gather: chunks of 4 edges = 192 float4 items; item = lane + 64*r ->
//   (edge = item/48, q = item%48, bs = q/24, f4 = q%24). Tail masked via w=0.

#define FMA4(A, W, V) \
    A.x += W * V.x; A.y += W * V.y; A.z += W * V.z; A.w += W * V.w;

__global__ __launch_bounds__(256) void k_fused(
    const float* __restrict__ x, const int* __restrict__ offs,
    const int2* __restrict__ cedge,
    const float* __restrict__ G, const float* __restrict__ C,
    const float* __restrict__ sm, const float* __restrict__ fcW,
    const float* __restrict__ fcb, float* __restrict__ out) {
    __shared__ float4 part[4][192];
    __shared__ float xals[4][2][96];
    __shared__ float hl[4][2][65];

    const int tid = threadIdx.x;
    const int wid = tid >> 6;
    const int lane = tid & 63;
    const int bp = blockIdx.x & 7;       // batch pair {bp, bp+8} -> XCD bp
    const int g = blockIdx.x >> 3;
    const int n = g * 4 + wid;

    int e0, e1, e2;
    unsigned off0, off1, off2;
    {
        int i0 = lane, i1 = lane + 64, i2 = lane + 128;
        e0 = i0 / 48; e1 = i1 / 48; e2 = i2 / 48;
        int q0 = i0 % 48, q1 = i1 % 48, q2 = i2 % 48;
        off0 = (unsigned)(q0 / 24) * BSOFF + (unsigned)(q0 % 24) * 16u;
        off1 = (unsigned)(q1 / 24) * BSOFF + (unsigned)(q1 % 24) * 16u;
        off2 = (unsigned)(q2 / 24) * BSOFF + (unsigned)(q2 % 24) * 16u;
    }

    const char* xbb = (const char*)x + (size_t)bp * XBSTRIDE;

    int r0 = __builtin_amdgcn_readfirstlane(offs[n]);
    int r1 = __builtin_amdgcn_readfirstlane(offs[n + 1]);
    int r1m1 = r1 - 1;

    float4 acc0 = {0.f, 0.f, 0.f, 0.f};
    float4 acc1 = {0.f, 0.f, 0.f, 0.f};
    float4 acc2 = {0.f, 0.f, 0.f, 0.f};

    for (int k = r0; k < r1; k += 4) {
        int i0 = k + e0, i1 = k + e1, i2 = k + e2;
        int c0 = min(i0, r1m1), c1 = min(i1, r1m1), c2 = min(i2, r1m1);
        int2 ce0 = cedge[c0];
        int2 ce1 = cedge[c1];
        int2 ce2 = cedge[c2];
        float w0 = (i0 <= r1m1) ? __int_as_float(ce0.y) : 0.f;
        float w1 = (i1 <= r1m1) ? __int_as_float(ce1.y) : 0.f;
        float w2 = (i2 <= r1m1) ? __int_as_float(ce2.y) : 0.f;
        float4 v0 = *(const float4*)(xbb + (unsigned)ce0.x * 384u + off0);
        float4 v1 = *(const float4*)(xbb + (unsigned)ce1.x * 384u + off1);
        float4 v2 = *(const float4*)(xbb + (unsigned)ce2.x * 384u + off2);
        FMA4(acc0, w0, v0)
        FMA4(acc1, w1, v1)
        FMA4(acc2, w2, v2)
    }
    part[wid][lane] = acc0;
    part[wid][lane + 64] = acc1;
    part[wid][lane + 128] = acc2;
    __syncthreads();
    if (lane < 48) {
        float4 a = part[wid][lane];
        float4 b4 = part[wid][lane + 48];
        float4 c4 = part[wid][lane + 96];
        float4 d4 = part[wid][lane + 144];
        float4 s4;
        s4.x = (a.x + b4.x) + (c4.x + d4.x);
        s4.y = (a.y + b4.y) + (c4.y + d4.y);
        s4.z = (a.z + b4.z) + (c4.z + d4.z);
        s4.w = (a.w + b4.w) + (c4.w + d4.w);
        *(float4*)&xals[wid][lane / 24][(lane % 24) * 4] = s4;
    }
    __syncthreads();

    // ---- dense gates: lane owns hidden channel o = lane; 2 batches
    float gz[FF], gh[FF];
#pragma unroll
    for (int f = 0; f < FF; ++f) {
        gz[f] = G[f * 64 + lane];
        gh[f] = G[512 + f * 64 + lane];
    }
    float cz = C[lane], ch = C[64 + lane];
    float smv[TT];
#pragma unroll
    for (int t = 0; t < TT; ++t) smv[t] = sm[t];

#pragma unroll
    for (int bs = 0; bs < 2; ++bs) {
        float hacc = 0.f;
#pragma unroll
        for (int tq = 0; tq < 3; ++tq) {
            float4 xq[FF];
#pragma unroll
            for (int f = 0; f < FF; ++f)
                xq[f] = *(const float4*)&xals[wid][bs][f * TT + tq * 4];  // broadcast b128
#pragma unroll
            for (int tt = 0; tt < 4; ++tt) {
                float az = cz, ah = ch;
#pragma unroll
                for (int f = 0; f < FF; ++f) {
                    float v = ((const float*)&xq[f])[tt];
                    az += v * gz[f];
                    ah += v * gh[f];
                }
                float z = 1.0f / (1.0f + __expf(-az));
                float th = 1.0f - 2.0f / (__expf(2.0f * ah) + 1.0f);
                hacc += smv[tq * 4 + tt] * (1.0f - z) * th;
            }
        }
        hl[wid][bs][lane] = hacc;
    }
    __syncthreads();

    // ---- fc: 4 nodes x 2 batches x 12 t = 96 outputs
    if (tid < 96) {
        int nw = tid / 24;
        int rem = tid % 24;
        int bs = rem / 12;
        int t = rem % 12;
        int nn2 = g * 4 + nw;
        int b = bp + bs * 8;
        float s = fcb[t];
#pragma unroll 16
        for (int o = 0; o < HH; ++o) s += hl[nw][bs][o] * fcW[o * TT + t];
        out[((size_t)b * NN + nn2) * TT + t] = s;
    }
}

extern "C" void kernel_launch(void* const* d_in, const int* in_sizes, int n_in,
                              void* d_out, int out_size, void* d_ws, size_t ws_size,
                              hipStream_t stream) {
    const float* x   = (const float*)d_in[0];
    const int*   ei  = (const int*)d_in[1];
    const float* Wz  = (const float*)d_in[2];
    const float* bz  = (const float*)d_in[3];
    const float* Lz  = (const float*)d_in[4];
    const float* lbz = (const float*)d_in[5];
    // d_in[6..9] = Wr, br, Lr, lbr : dead (H == 0)
    const float* Wh  = (const float*)d_in[10];
    const float* bh  = (const float*)d_in[11];
    const float* Lh  = (const float*)d_in[12];
    const float* lbh = (const float*)d_in[13];
    const float* att = (const float*)d_in[14];
    const float* fcW = (const float*)d_in[15];
    const float* fcb = (const float*)d_in[16];
    float* out = (float*)d_out;

    const int* src = ei;
    const int* dst = ei + EE;

    int2*  cedge  = (int2*)d_ws;           // EN (8B each, 8B-aligned at ws base)
    int*   deg    = (int*)(cedge + EN);    // N
    int*   cursor = deg + NN;              // N
    int*   offs   = cursor + NN;           // N+1
    float* dinv   = (float*)(offs + NN + 1); // N
    float* G      = dinv + NN;             // 2*8*64
    float* C      = G + 1024;              // 2*64
    float* sm     = C + 128;               // T

    hipMemsetAsync(deg, 0, NN * sizeof(int), stream);
    hipLaunchKernelGGL(k_count, dim3((EE + 255) / 256), dim3(256), 0, stream, dst, deg);
    hipLaunchKernelGGL(k_scan_prep, dim3(2), dim3(256), 0, stream,
                       deg, offs, cursor, dinv,
                       Wz, bz, Lz, lbz, Wh, bh, Lh, lbh, att, G, C, sm);
    hipLaunchKernelGGL(k_fill, dim3((EN + 255) / 256), dim3(256), 0, stream,
                       src, dst, cursor, dinv, cedge);
    hipLaunchKernelGGL(k_fused, dim3(1250 * 8), dim3(256), 0, stream,
                       x, offs, cedge, G, C, sm, fcW, fcb, out);
}

// Round 4
// 142.918 us; speedup vs baseline: 1.7102x; 1.3322x over previous
//
#include <hip/hip_runtime.h>
#include <math.h>

#define BB 16
#define NN 5000
#define FF 8
#define TT 12
#define EE 160000
#define HH 64
#define EN (EE + NN)
#define XBSTRIDE 1920000      // bytes per batch slab of x (N*F*T*4)
#define BSOFF    15360000     // 8 slabs = byte offset from batch b to b+8

// ---------------- CSR build ----------------

__global__ void k_count(const int* __restrict__ dst, int* __restrict__ deg) {
    int i = blockIdx.x * blockDim.x + threadIdx.x;
    if (i < EE) atomicAdd(&deg[dst[i]], 1);
}

// block 0: CSR offsets + dinv scan; block 1: weight folding + softmax
__global__ __launch_bounds__(256) void k_scan_prep(
    const int* __restrict__ deg, int* __restrict__ offs, int* __restrict__ cursor,
    float* __restrict__ dinv,
    const float* __restrict__ Wz, const float* __restrict__ bz,
    const float* __restrict__ Lz, const float* __restrict__ lbz,
    const float* __restrict__ Wh, const float* __restrict__ bh,
    const float* __restrict__ Lh, const float* __restrict__ lbh,
    const float* __restrict__ att,
    float* __restrict__ G, float* __restrict__ C, float* __restrict__ sm) {
    int tid = threadIdx.x;
    if (blockIdx.x == 0) {
        __shared__ int s[256];
        int base = tid * 20;
        int cnt[20];
        int part = 0;
#pragma unroll
        for (int j = 0; j < 20; ++j) {
            int n = base + j;
            int c = (n < NN) ? deg[n] + 1 : 0;   // +1 self loop
            cnt[j] = c;
            part += c;
        }
        s[tid] = part;
        __syncthreads();
        for (int d = 1; d < 256; d <<= 1) {
            int v = (tid >= d) ? s[tid - d] : 0;
            __syncthreads();
            s[tid] += v;
            __syncthreads();
        }
        int run = s[tid] - part;  // exclusive prefix
#pragma unroll
        for (int j = 0; j < 20; ++j) {
            int n = base + j;
            if (n < NN) {
                offs[n] = run;
                cursor[n] = run;
                dinv[n] = rsqrtf((float)cnt[j]);
                run += cnt[j];
            }
        }
        if (tid == 255) offs[NN] = s[255];
    } else {
        // G = W @ L[:64]  (two gates), C = b @ L[:64] + lb
        for (int idx = tid; idx < 1024; idx += 256) {
            int g = idx >> 9, rem = idx & 511, f = rem >> 6, o = rem & 63;
            const float* W = g ? Wh : Wz;
            const float* L = g ? Lh : Lz;
            float acc = 0.f;
            for (int k = 0; k < 64; ++k) acc += W[f * 64 + k] * L[k * 64 + o];
            G[idx] = acc;
        }
        for (int idx = tid; idx < 128; idx += 256) {
            int g = idx >> 6, o = idx & 63;
            const float* b = g ? bh : bz;
            const float* L = g ? Lh : Lz;
            const float* lb = g ? lbh : lbz;
            float acc = lb[o];
            for (int k = 0; k < 64; ++k) acc += b[k] * L[k * 64 + o];
            C[idx] = acc;
        }
        if (tid == 0) {
            float m = att[0];
            for (int t = 1; t < TT; ++t) m = fmaxf(m, att[t]);
            float e[TT], ss = 0.f;
            for (int t = 0; t < TT; ++t) { e[t] = __expf(att[t] - m); ss += e[t]; }
            for (int t = 0; t < TT; ++t) sm[t] = e[t] / ss;
        }
    }
}

__global__ void k_fill(const int* __restrict__ src, const int* __restrict__ dst,
                       int* cursor, const float* __restrict__ dinv,
                       int2* __restrict__ cedge) {
    int i = blockIdx.x * blockDim.x + threadIdx.x;
    if (i < EE) {
        int s = src[i], d = dst[i];
        int p = atomicAdd(&cursor[d], 1);
        cedge[p] = make_int2(s, __float_as_int(dinv[s] * dinv[d]));
    } else if (i < EN) {
        int n = i - EE;
        int p = atomicAdd(&cursor[n], 1);
        cedge[p] = make_int2(n, __float_as_int(dinv[n] * dinv[n]));
    } else if (i < EN + 8) {
        cedge[i] = make_int2(0, 0);   // prefetch pad (w=0-equivalent, valid node 0)
    }
}

// ---------------- fused gather + gates + attention + fc ----------------
// blockIdx % 8 = bp  -> XCD bp only touches batches {bp, bp+8}: 3.84 MB, L2-resident.
// block = 4 waves; wave = one node, 2 batches.
// Gather: edge list walked with wave-UNIFORM (SGPR) cedge loads, prefetched one
// 4-chunk ahead. Lane (<48) owns one float4: bs = lane/24, f4 = lane%24.
// Per edge: scalar node*384 + invariant voff -> one v_add + one global_load +
// 4 v_fmac with SGPR weight. No masks, no cross-lane reduce.

#define EDGE(D)                                                         \
    {                                                                   \
        unsigned a_ = (unsigned)(D).x * 384u + voff;                    \
        float4 v_ = *(const float4*)(xbb + a_);                         \
        float w_ = __int_as_float((D).y);                               \
        acc.x += w_ * v_.x; acc.y += w_ * v_.y;                         \
        acc.z += w_ * v_.z; acc.w += w_ * v_.w;                         \
    }

__global__ __launch_bounds__(256) void k_fused(
    const float* __restrict__ x, const int* __restrict__ offs,
    const int2* __restrict__ cedge,
    const float* __restrict__ G, const float* __restrict__ C,
    const float* __restrict__ sm, const float* __restrict__ fcW,
    const float* __restrict__ fcb, float* __restrict__ out) {
    __shared__ __align__(16) float xals[4][2][96];
    __shared__ float hl[4][2][65];

    const int tid = threadIdx.x;
    const int wid = tid >> 6;
    const int lane = tid & 63;
    const int bp = blockIdx.x & 7;       // batch pair {bp, bp+8} -> XCD bp
    const int g = blockIdx.x >> 3;
    const int n = g * 4 + wid;

    int r0 = __builtin_amdgcn_readfirstlane(offs[n]);
    int r1 = __builtin_amdgcn_readfirstlane(offs[n + 1]);

    const char* xbb = (const char*)x + (size_t)bp * XBSTRIDE;

    if (lane < 48) {
        const unsigned voff = (unsigned)(lane / 24) * BSOFF + (unsigned)(lane % 24) * 16u;
        float4 acc = {0.f, 0.f, 0.f, 0.f};

        int k = r0;
        int2 p0 = cedge[k];
        int2 p1 = cedge[k + 1];
        int2 p2 = cedge[k + 2];
        int2 p3 = cedge[k + 3];
        while (k + 4 <= r1) {
            int2 d0 = p0, d1 = p1, d2 = p2, d3 = p3;
            k += 4;
            p0 = cedge[k];
            p1 = cedge[k + 1];
            p2 = cedge[k + 2];
            p3 = cedge[k + 3];
            EDGE(d0) EDGE(d1) EDGE(d2) EDGE(d3)
        }
        int rem = r1 - k;        // 0..3, wave-uniform
        if (rem > 0) EDGE(p0)
        if (rem > 1) EDGE(p1)
        if (rem > 2) EDGE(p2)

        *(float4*)&xals[wid][lane / 24][(lane % 24) * 4] = acc;
    }
    __syncthreads();

    // ---- dense gates: lane owns hidden channel o = lane; 2 batches
    float gz[FF], gh[FF];
#pragma unroll
    for (int f = 0; f < FF; ++f) {
        gz[f] = G[f * 64 + lane];
        gh[f] = G[512 + f * 64 + lane];
    }
    float cz = C[lane], ch = C[64 + lane];
    float smv[TT];
#pragma unroll
    for (int t = 0; t < TT; ++t) smv[t] = sm[t];

#pragma unroll
    for (int bs = 0; bs < 2; ++bs) {
        float hacc = 0.f;
#pragma unroll
        for (int tq = 0; tq < 3; ++tq) {
            float4 xq[FF];
#pragma unroll
            for (int f = 0; f < FF; ++f)
                xq[f] = *(const float4*)&xals[wid][bs][f * TT + tq * 4];  // broadcast b128
#pragma unroll
            for (int tt = 0; tt < 4; ++tt) {
                float az = cz, ah = ch;
#pragma unroll
                for (int f = 0; f < FF; ++f) {
                    float v = ((const float*)&xq[f])[tt];
                    az += v * gz[f];
                    ah += v * gh[f];
                }
                // fast sigmoid / tanh: v_exp + v_rcp, no precise-div sequences
                float z = __builtin_amdgcn_rcpf(1.0f + __expf(-az));
                float th = 1.0f - 2.0f * __builtin_amdgcn_rcpf(__expf(2.0f * ah) + 1.0f);
                hacc += smv[tq * 4 + tt] * (1.0f - z) * th;
            }
        }
        hl[wid][bs][lane] = hacc;
    }
    __syncthreads();

    // ---- fc: 4 nodes x 2 batches x 12 t = 96 outputs
    if (tid < 96) {
        int nw = tid / 24;
        int rem = tid % 24;
        int bs = rem / 12;
        int t = rem % 12;
        int nn2 = g * 4 + nw;
        int b = bp + bs * 8;
        float s = fcb[t];
#pragma unroll 16
        for (int o = 0; o < HH; ++o) s += hl[nw][bs][o] * fcW[o * TT + t];
        out[((size_t)b * NN + nn2) * TT + t] = s;
    }
}

extern "C" void kernel_launch(void* const* d_in, const int* in_sizes, int n_in,
                              void* d_out, int out_size, void* d_ws, size_t ws_size,
                              hipStream_t stream) {
    const float* x   = (const float*)d_in[0];
    const int*   ei  = (const int*)d_in[1];
    const float* Wz  = (const float*)d_in[2];
    const float* bz  = (const float*)d_in[3];
    const float* Lz  = (const float*)d_in[4];
    const float* lbz = (const float*)d_in[5];
    // d_in[6..9] = Wr, br, Lr, lbr : dead (H == 0)
    const float* Wh  = (const float*)d_in[10];
    const float* bh  = (const float*)d_in[11];
    const float* Lh  = (const float*)d_in[12];
    const float* lbh = (const float*)d_in[13];
    const float* att = (const float*)d_in[14];
    const float* fcW = (const float*)d_in[15];
    const float* fcb = (const float*)d_in[16];
    float* out = (float*)d_out;

    const int* src = ei;
    const int* dst = ei + EE;

    int2*  cedge  = (int2*)d_ws;             // EN + 8 pad (8B each)
    int*   deg    = (int*)(cedge + EN + 8);  // N
    int*   cursor = deg + NN;                // N
    int*   offs   = cursor + NN;             // N+1
    float* dinv   = (float*)(offs + NN + 1); // N
    float* G      = dinv + NN;               // 2*8*64
    float* C      = G + 1024;                // 2*64
    float* sm     = C + 128;                 // T

    hipMemsetAsync(deg, 0, NN * sizeof(int), stream);
    hipLaunchKernelGGL(k_count, dim3((EE + 255) / 256), dim3(256), 0, stream, dst, deg);
    hipLaunchKernelGGL(k_scan_prep, dim3(2), dim3(256), 0, stream,
                       deg, offs, cursor, dinv,
                       Wz, bz, Lz, lbz, Wh, bh, Lh, lbh, att, G, C, sm);
    hipLaunchKernelGGL(k_fill, dim3((EN + 8 + 255) / 256), dim3(256), 0, stream,
                       src, dst, cursor, dinv, cedge);
    hipLaunchKernelGGL(k_fused, dim3(1250 * 8), dim3(256), 0, stream,
                       x, offs, cedge, G, C, sm, fcW, fcb, out);
}

// Round 6
// 137.462 us; speedup vs baseline: 1.7781x; 1.0397x over previous
//
#include <hip/hip_runtime.h>

#define NN 5000
#define FF 8
#define TT 12
#define EE 160000
#define HH 64
#define EN (EE + NN)
#define CAP (EN + 7 * NN + 64)   // padded edge capacity + prefetch slack
#define XBSTRIDE 1920000         // bytes per batch slab of x (N*F*T*4)
#define BSOFF    15360000        // 8 slabs = byte offset from batch b to b+8

typedef float f2  __attribute__((ext_vector_type(2)));
typedef float f4v __attribute__((ext_vector_type(4)));

#define LOG2E 1.44269504088896340736f

// ---------------- CSR build ----------------

__global__ void k_count(const int* __restrict__ dst, int* __restrict__ deg) {
    int i = blockIdx.x * blockDim.x + threadIdx.x;
    if (i < EE) atomicAdd(&deg[dst[i]], 1);
}

// block 0: CSR offsets (padded to 8) + dinv scan; block 1: weight folding + softmax
__global__ __launch_bounds__(256) void k_scan_prep(
    const int* __restrict__ deg, int* __restrict__ offs, int* __restrict__ cursor,
    float* __restrict__ dinv,
    const float* __restrict__ Wz, const float* __restrict__ bz,
    const float* __restrict__ Lz, const float* __restrict__ lbz,
    const float* __restrict__ Wh, const float* __restrict__ bh,
    const float* __restrict__ Lh, const float* __restrict__ lbh,
    const float* __restrict__ att,
    float* __restrict__ G, float* __restrict__ C, float* __restrict__ sm) {
    int tid = threadIdx.x;
    if (blockIdx.x == 0) {
        __shared__ int s[256];
        int base = tid * 20;
        int pad[20], real[20];
        int part = 0;
#pragma unroll
        for (int j = 0; j < 20; ++j) {
            int n = base + j;
            int c = (n < NN) ? deg[n] + 1 : 0;   // +1 self loop
            real[j] = c;
            pad[j] = (c + 7) & ~7;               // pad to multiple of 8 entries
            part += pad[j];
        }
        s[tid] = part;
        __syncthreads();
        for (int d = 1; d < 256; d <<= 1) {
            int v = (tid >= d) ? s[tid - d] : 0;
            __syncthreads();
            s[tid] += v;
            __syncthreads();
        }
        int run = s[tid] - part;  // exclusive prefix
#pragma unroll
        for (int j = 0; j < 20; ++j) {
            int n = base + j;
            if (n < NN) {
                offs[n] = run;
                cursor[n] = run;
                dinv[n] = rsqrtf((float)real[j]);
                run += pad[j];
            }
        }
        if (tid == 255) offs[NN] = s[255];
    } else {
        // G = W @ L[:64] (two gates), C = b @ L[:64] + lb; pre-scaled by log2e
        // (z gate) and 2*log2e (h gate) so the dense phase uses raw exp2.
        for (int idx = tid; idx < 1024; idx += 256) {
            int g = idx >> 9, rem = idx & 511, f = rem >> 6, o = rem & 63;
            const float* W = g ? Wh : Wz;
            const float* L = g ? Lh : Lz;
            float acc = 0.f;
            for (int k = 0; k < 64; ++k) acc += W[f * 64 + k] * L[k * 64 + o];
            G[idx] = acc * (g ? 2.0f * LOG2E : LOG2E);
        }
        for (int idx = tid; idx < 128; idx += 256) {
            int g = idx >> 6, o = idx & 63;
            const float* b = g ? bh : bz;
            const float* L = g ? Lh : Lz;
            const float* lb = g ? lbh : lbz;
            float acc = lb[o];
            for (int k = 0; k < 64; ++k) acc += b[k] * L[k * 64 + o];
            C[idx] = acc * (g ? 2.0f * LOG2E : LOG2E);
        }
        if (tid == 0) {
            float m = att[0];
            for (int t = 1; t < TT; ++t) m = fmaxf(m, att[t]);
            float e[TT], ss = 0.f;
            for (int t = 0; t < TT; ++t) { e[t] = __expf(att[t] - m); ss += e[t]; }
            for (int t = 0; t < TT; ++t) sm[t] = e[t] / ss;
        }
    }
}

__global__ void k_fill(const int* __restrict__ src, const int* __restrict__ dst,
                       int* cursor, const float* __restrict__ dinv,
                       int2* __restrict__ cedge) {
    int i = blockIdx.x * blockDim.x + threadIdx.x;
    if (i < EE) {
        int s = src[i], d = dst[i];
        int p = atomicAdd(&cursor[d], 1);
        cedge[p] = make_int2(s, __float_as_int(dinv[s] * dinv[d]));
    } else if (i < EN) {
        int n = i - EE;
        int p = atomicAdd(&cursor[n], 1);
        cedge[p] = make_int2(n, __float_as_int(dinv[n] * dinv[n]));
    }
    // pad entries stay (0, 0.0f) from the memset: node 0, weight 0 -> no-op.
}

// ---------------- fused gather + gates + attention + fc ----------------
// blockIdx % 8 = bp  -> XCD bp only touches batches {bp, bp+8}: L2-resident.
// block = 4 waves; wave = one node, 2 batches; lane<48 owns one float4.
// Edge lists padded to 8-entry multiples: no tails; wave-uniform int4 chunk
// loads (SGPR) with 2-iteration rotating prefetch.

#define E2(Q)                                                     \
    {                                                             \
        unsigned a0_ = (unsigned)(Q).x * 384u + voff;             \
        unsigned a1_ = (unsigned)(Q).z * 384u + voff;             \
        f4v v0_ = *(const f4v*)(xbb + a0_);                       \
        f4v v1_ = *(const f4v*)(xbb + a1_);                       \
        acc += __int_as_float((Q).y) * v0_;                       \
        acc += __int_as_float((Q).w) * v1_;                       \
    }

__global__ __launch_bounds__(256) void k_fused(
    const float* __restrict__ x, const int* __restrict__ offs,
    const int2* __restrict__ cedge,
    const float* __restrict__ G, const float* __restrict__ C,
    const float* __restrict__ sm, const float* __restrict__ fcW,
    const float* __restrict__ fcb, float* __restrict__ out) {
    __shared__ __align__(16) float xals[4][2][96];
    __shared__ __align__(16) float hl[4][2][72];   // 72: 16B-aligned rows, staggered banks
    __shared__ __align__(16) float fcw[768];
    __shared__ __align__(16) float Glds[1024];
    __shared__ __align__(16) float Clds[128];

    const int tid = threadIdx.x;
    const int wid = tid >> 6;
    const int lane = tid & 63;
    const int bp = blockIdx.x & 7;       // batch pair {bp, bp+8} -> XCD bp
    const int g = blockIdx.x >> 3;
    const int n = g * 4 + wid;

    // stage weights into LDS (complete before first __syncthreads)
    ((f4v*)Glds)[tid] = ((const f4v*)G)[tid];
    if (tid < 192) ((f4v*)fcw)[tid] = ((const f4v*)fcW)[tid];
    if (tid < 32) ((f4v*)Clds)[tid] = ((const f4v*)C)[tid];

    int r0 = __builtin_amdgcn_readfirstlane(offs[n]);
    int r1 = __builtin_amdgcn_readfirstlane(offs[n + 1]);

    const char* xbb = (const char*)x + (size_t)bp * XBSTRIDE;

    if (lane < 48) {
        const unsigned voff = (unsigned)(lane / 24) * BSOFF + (unsigned)(lane % 24) * 16u;
        f4v acc = {0.f, 0.f, 0.f, 0.f};

        const int4* ce = (const int4*)cedge;   // 2 edges per int4
        int c = r0 >> 1;                       // int4 index, multiple of 4
        const int c1 = r1 >> 1;
        int4 A0 = ce[c], A1 = ce[c + 1], A2 = ce[c + 2], A3 = ce[c + 3];
        int4 B0 = ce[c + 4], B1 = ce[c + 5], B2 = ce[c + 6], B3 = ce[c + 7];
        while (true) {
            int4 D0 = A0, D1 = A1, D2 = A2, D3 = A3;
            A0 = B0; A1 = B1; A2 = B2; A3 = B3;
            B0 = ce[c + 8]; B1 = ce[c + 9]; B2 = ce[c + 10]; B3 = ce[c + 11];
            E2(D0) E2(D1) E2(D2) E2(D3)
            c += 4;
            if (c >= c1) break;
        }
        *(f4v*)&xals[wid][lane / 24][(lane % 24) * 4] = acc;
    }
    __syncthreads();

    // ---- dense gates (lane = hidden channel o); packed f2 over t-pairs.
    // az,ah are pre-scaled by log2e/2log2e; (1-z)*tanh = (e2h-1)/((1+ea)(1+e2h)).
    float gz[FF], gh[FF];
#pragma unroll
    for (int f = 0; f < FF; ++f) {
        gz[f] = Glds[f * 64 + lane];
        gh[f] = Glds[512 + f * 64 + lane];
    }
    float cz = Clds[lane], ch = Clds[64 + lane];
    float smv[TT];
#pragma unroll
    for (int t = 0; t < TT; ++t) smv[t] = sm[t];

#pragma unroll
    for (int bs = 0; bs < 2; ++bs) {
        float hacc = 0.f;
#pragma unroll
        for (int tq = 0; tq < 3; ++tq) {
            f4v xq[FF];
#pragma unroll
            for (int f = 0; f < FF; ++f)
                xq[f] = *(const f4v*)&xals[wid][bs][f * TT + tq * 4];  // broadcast b128
#pragma unroll
            for (int half = 0; half < 2; ++half) {
                f2 az = {cz, cz}, ah = {ch, ch};
#pragma unroll
                for (int f = 0; f < FF; ++f) {
                    f2 v = half ? xq[f].hi : xq[f].lo;
                    az += v * gz[f];
                    ah += v * gh[f];
                }
#pragma unroll
                for (int j = 0; j < 2; ++j) {
                    float ea = exp2f(az[j]);    // v_exp_f32
                    float e2h = exp2f(ah[j]);   // v_exp_f32
                    float num = e2h - 1.0f;
                    float den = (1.0f + ea) * (1.0f + e2h);
                    hacc += smv[tq * 4 + half * 2 + j] * num * __builtin_amdgcn_rcpf(den);
                }
            }
        }
        hl[wid][bs][lane] = hacc;
    }
    __syncthreads();

    // ---- fc: 4 nodes x 2 batches x 6 t-pairs = 48 threads, packed f2
    if (tid < 48) {
        int nw = tid / 12;
        int rem = tid % 12;
        int bs = rem / 6;
        int tp = rem % 6;
        f2 acc;
        acc[0] = fcb[2 * tp];
        acc[1] = fcb[2 * tp + 1];
        const float* hrow = &hl[nw][bs][0];
#pragma unroll
        for (int o4 = 0; o4 < 16; ++o4) {
            f4v h4 = *(const f4v*)&hrow[o4 * 4];
            f2 w0 = *(const f2*)&fcw[(o4 * 4 + 0) * TT + 2 * tp];
            f2 w1 = *(const f2*)&fcw[(o4 * 4 + 1) * TT + 2 * tp];
            f2 w2 = *(const f2*)&fcw[(o4 * 4 + 2) * TT + 2 * tp];
            f2 w3 = *(const f2*)&fcw[(o4 * 4 + 3) * TT + 2 * tp];
            acc += h4[0] * w0;
            acc += h4[1] * w1;
            acc += h4[2] * w2;
            acc += h4[3] * w3;
        }
        int b = bp + bs * 8;
        int nn2 = g * 4 + nw;
        *(f2*)&out[((size_t)b * NN + nn2) * TT + 2 * tp] = acc;
    }
}

extern "C" void kernel_launch(void* const* d_in, const int* in_sizes, int n_in,
                              void* d_out, int out_size, void* d_ws, size_t ws_size,
                              hipStream_t stream) {
    const float* x   = (const float*)d_in[0];
    const int*   ei  = (const int*)d_in[1];
    const float* Wz  = (const float*)d_in[2];
    const float* bz  = (const float*)d_in[3];
    const float* Lz  = (const float*)d_in[4];
    const float* lbz = (const float*)d_in[5];
    // d_in[6..9] = Wr, br, Lr, lbr : dead (H == 0)
    const float* Wh  = (const float*)d_in[10];
    const float* bh  = (const float*)d_in[11];
    const float* Lh  = (const float*)d_in[12];
    const float* lbh = (const float*)d_in[13];
    const float* att = (const float*)d_in[14];
    const float* fcW = (const float*)d_in[15];
    const float* fcb = (const float*)d_in[16];
    float* out = (float*)d_out;

    const int* src = ei;
    const int* dst = ei + EE;

    int2*  cedge  = (int2*)d_ws;             // CAP entries (zeroed each call)
    int*   deg    = (int*)(cedge + CAP);     // N (zeroed by same memset)
    int*   cursor = deg + NN;                // N
    int*   offs   = cursor + NN;             // N+1
    float* dinv   = (float*)(offs + NN + 1); // N
    float* G      = dinv + NN;               // 2*8*64
    float* C      = G + 1024;                // 2*64
    float* sm     = C + 128;                 // T

    (void)hipMemsetAsync(d_ws, 0, (size_t)CAP * 8 + (size_t)NN * 4, stream);
    hipLaunchKernelGGL(k_count, dim3((EE + 255) / 256), dim3(256), 0, stream, dst, deg);
    hipLaunchKernelGGL(k_scan_prep, dim3(2), dim3(256), 0, stream,
                       deg, offs, cursor, dinv,
                       Wz, bz, Lz, lbz, Wh, bh, Lh, lbh, att, G, C, sm);
    hipLaunchKernelGGL(k_fill, dim3((EN + 255) / 256), dim3(256), 0, stream,
                       src, dst, cursor, dinv, cedge);
    hipLaunchKernelGGL(k_fused, dim3(1250 * 8), dim3(256), 0, stream,
                       x, offs, cedge, G, C, sm, fcW, fcb, out);
}